// Round 5
// baseline (148.505 us; speedup 1.0000x reference)
//
#include <hip/hip_runtime.h>
#include <math.h>

#define B_ 4
#define N_ 1024
#define M_ 2048
#define D_ 9
#define K_ 64
#define BM_ (B_*M_)   // 8192 targets
#define BN_ (B_*N_)   // 4096 preds
#define TPRE_STRIDE 12
#define PPRE_STRIDE 12
#define NPART 32      // stats partial blocks
#define NSTAT 55      // 1 + 9 + 45 accumulators
#define TSEL 1024     // select kernel block size (16 waves)

// workspace layout (in floats)
#define WS_A 0                                   // 81: cov_inv (symmetric)
#define WS_MEAN 81                               // 9
#define WS_TPRE 96                               // 8192*12: [Au(9), uAu, pad, pad]
#define WS_PPRE (WS_TPRE + BM_*TPRE_STRIDE)      // 4096*12: [Aq(9), qAq, yAy, pad]
#define WS_CS_INTRA (WS_PPRE + BN_*PPRE_STRIDE)  // 1024 per-column sums
#define WS_CS_INTER (WS_CS_INTRA + N_)           // 1024
#define WS_PART (WS_CS_INTER + N_)               // 32*56 stats partials

__device__ __forceinline__ unsigned f2key(float f) {
  unsigned b = __float_as_uint(f);
  return (b & 0x80000000u) ? ~b : (b | 0x80000000u);
}
__device__ __forceinline__ float key2f(unsigned k) {
  unsigned b = (k & 0x80000000u) ? (k ^ 0x80000000u) : ~k;
  return __uint_as_float(b);
}

// mask dtype auto-detect from first 8192 bytes (always in-bounds for
// u8/i32/i64 layouts). 0 = u8/bool, 1 = int32, 2 = int64.
__device__ int detect_mask_fmt(const void* mask, int* flags /*shared[2]*/) {
  int tid = threadIdx.x;
  if (tid < 2) flags[tid] = 0;
  __syncthreads();
  const unsigned char* mb = (const unsigned char*)mask;
  int la = 0, lb = 0;
  for (int i = tid; i < BM_; i += blockDim.x) {
    unsigned char c = mb[i];
    if (c) { if (i & 3) la = 1; else if ((i & 7) == 4) lb = 1; }
  }
  if (la) atomicOr(&flags[0], 1);
  if (lb) atomicOr(&flags[1], 1);
  __syncthreads();
  return flags[0] ? 0 : (flags[1] ? 1 : 2);
}
__device__ __forceinline__ int mask_at(const void* mask, int fmt, int t) {
  if (fmt == 0) return ((const unsigned char*)mask)[t] != 0;
  if (fmt == 1) return ((const int*)mask)[t] != 0;
  return ((const long long*)mask)[t] != 0LL;
}

// -------- kernel 1a: per-block partial stats (S, Σt, Σ t tᵀ) in f32 --------
__global__ __launch_bounds__(256) void stats_part_kernel(
    const float* __restrict__ targets, const void* __restrict__ mask,
    float* __restrict__ ws) {
  __shared__ int flags[2];
  __shared__ float wpart[4][NSTAT];
  int tid = threadIdx.x;
  int fmt = detect_mask_fmt(mask, flags);
  int t = blockIdx.x * 256 + tid;  // one target per thread (BM_ = 32*256)

  float v[NSTAT];
  float tv[D_];
  int m = mask_at(mask, fmt, t);
  const float* tp = targets + t * D_;
#pragma unroll
  for (int d = 0; d < D_; ++d) tv[d] = m ? tp[d] : 0.f;
  v[0] = m ? 1.f : 0.f;
#pragma unroll
  for (int d = 0; d < D_; ++d) v[1 + d] = tv[d];
  {
    int p = 10;
#pragma unroll
    for (int i = 0; i < D_; ++i)
#pragma unroll
      for (int j = i; j < D_; ++j, ++p) v[p] = tv[i] * tv[j];
  }
#pragma unroll
  for (int off = 32; off > 0; off >>= 1)
#pragma unroll
    for (int p = 0; p < NSTAT; ++p) v[p] += __shfl_down(v[p], off);
  int wave = tid >> 6, lane = tid & 63;
  if (lane == 0)
#pragma unroll
    for (int p = 0; p < NSTAT; ++p) wpart[wave][p] = v[p];
  __syncthreads();
  if (tid < NSTAT) {
    float s = wpart[0][tid] + wpart[1][tid] + wpart[2][tid] + wpart[3][tid];
    ws[WS_PART + blockIdx.x * (NSTAT + 1) + tid] = s;
  }
}

// -------- kernel 1b: combine partials; lane-parallel f32 Gauss-Jordan --------
// Covariance is SPD (cond ~1 for standard-normal targets) -> no pivoting.
__global__ __launch_bounds__(64) void stats_fin_kernel(float* __restrict__ ws) {
  __shared__ float tot[NSTAT];
  __shared__ float Atmp[9][9];
  int lane = threadIdx.x;
  if (lane < NSTAT) {
    double s = 0.0;
    for (int b = 0; b < NPART; ++b)
      s += (double)ws[WS_PART + b * (NSTAT + 1) + lane];
    tot[lane] = (float)s;
  }
  __syncthreads();
  float S = tot[0];
  float col[9];
  int j = lane - 9;
  if (lane < 9) {
    float mj = tot[1 + lane] / S;
#pragma unroll
    for (int r = 0; r < 9; ++r) {
      float mr = tot[1 + r] / S;
      int i0 = r < lane ? r : lane;
      int j0 = r < lane ? lane : r;
      int p = i0 * 9 - (i0 * (i0 - 1)) / 2 + (j0 - i0);
      col[r] = (tot[10 + p] - S * mr * mj) / (S - 1.0f);
    }
  } else {
#pragma unroll
    for (int r = 0; r < 9; ++r) col[r] = (r == j) ? 1.f : 0.f;
  }
#pragma unroll
  for (int c = 0; c < 9; ++c) {
    float pv = __shfl(col[c], c);
    float inv = 1.f / pv;
    col[c] *= inv;
    float f[9];
#pragma unroll
    for (int r = 0; r < 9; ++r) f[r] = __shfl(col[r], c);
#pragma unroll
    for (int r = 0; r < 9; ++r)
      if (r != c) col[r] -= f[r] * col[c];
  }
  if (lane >= 9 && lane < 18) {
#pragma unroll
    for (int r = 0; r < 9; ++r) Atmp[r][j] = col[r];
  }
  __syncthreads();
  if (lane < 9) ws[WS_MEAN + lane] = tot[1 + lane] / S;
  for (int idx = lane; idx < 81; idx += 64) {
    int i0 = idx / 9, j0 = idx % 9;
    ws[WS_A + idx] = 0.5f * (Atmp[i0][j0] + Atmp[j0][i0]);
  }
}

// ---------------- kernel 2: precompute factored terms ----------------
__global__ __launch_bounds__(256) void pre_kernel(
    const float* __restrict__ outputs, const float* __restrict__ targets,
    const void* __restrict__ mask, float* __restrict__ ws) {
  __shared__ int flags[2];
  __shared__ float Ash[81];
  __shared__ float msh[D_];
  int tid = threadIdx.x;
  int fmt = detect_mask_fmt(mask, flags);
  if (tid < 81) Ash[tid] = ws[WS_A + tid];
  if (tid < D_) msh[tid] = ws[WS_MEAN + tid];
  __syncthreads();
  int idx = blockIdx.x * 256 + tid;
  if (idx < BM_) {
    const float* tp = targets + idx * D_;
    float u[D_];
#pragma unroll
    for (int d = 0; d < D_; ++d) u[d] = tp[d] - msh[d];
    float cu = 0.f; float au[D_];
#pragma unroll
    for (int i = 0; i < D_; ++i) {
      float s = 0.f;
#pragma unroll
      for (int j = 0; j < D_; ++j) s += Ash[i * D_ + j] * u[j];
      au[i] = s; cu += u[i] * s;
    }
    if (!mask_at(mask, fmt, idx)) cu = INFINITY;
    float* o = ws + WS_TPRE + idx * TPRE_STRIDE;
#pragma unroll
    for (int d = 0; d < D_; ++d) o[d] = au[d];
    o[9] = cu; o[10] = 0.f; o[11] = 0.f;
  } else if (idx < BM_ + BN_) {
    int r = idx - BM_;
    const float* yp = outputs + r * D_;
    float y[D_], q[D_], aq[D_];
#pragma unroll
    for (int d = 0; d < D_; ++d) { y[d] = yp[d]; q[d] = y[d] + msh[d]; }
    float cp = 0.f, cq = 0.f;
#pragma unroll
    for (int i = 0; i < D_; ++i) {
      float sy = 0.f, sq = 0.f;
#pragma unroll
      for (int j = 0; j < D_; ++j) {
        sy += Ash[i * D_ + j] * y[j];
        sq += Ash[i * D_ + j] * q[j];
      }
      cp += y[i] * sy;
      aq[i] = sq; cq += q[i] * sq;
    }
    float* o = ws + WS_PPRE + r * PPRE_STRIDE;
#pragma unroll
    for (int d = 0; d < D_; ++d) o[d] = aq[d];
    o[9] = cq; o[10] = cp; o[11] = 0.f;
  }
}

// ---- wave-uniform bisection for the exact K_-th smallest key; ballot-count,
// ---- zero barriers. Returns T (an existing key).
template <int PER>
__device__ __forceinline__ unsigned bisect64(const unsigned* key) {
  unsigned kmin = 0xFFFFFFFFu, kmax = 0u;
#pragma unroll
  for (int j = 0; j < PER; ++j) {
    kmin = key[j] < kmin ? key[j] : kmin;
    kmax = key[j] > kmax ? key[j] : kmax;
  }
#pragma unroll
  for (int off = 32; off > 0; off >>= 1) {
    unsigned a = (unsigned)__shfl_xor((int)kmin, off);
    unsigned b = (unsigned)__shfl_xor((int)kmax, off);
    kmin = a < kmin ? a : kmin;
    kmax = b > kmax ? b : kmax;
  }
  unsigned lo = kmin, hi = kmax;
  while (lo < hi) {  // wave-uniform
    unsigned mid = lo + ((hi - lo) >> 1);
    int cnt = 0;
#pragma unroll
    for (int j = 0; j < PER; ++j) cnt += __popcll(__ballot(key[j] <= mid));
    if (cnt >= K_) hi = mid; else lo = mid + 1;
  }
  return lo;
}

// ---- per-wave exact top-64 multiset -> 64-slot LDS region ----
template <int PER>
__device__ __forceinline__ void wave_top64(const unsigned* key,
                                           float* __restrict__ candw,
                                           int lane) {
  unsigned T = bisect64<PER>(key);
  unsigned long long lmask = (1ull << lane) - 1ull;
  int nlt = 0;
#pragma unroll
  for (int j = 0; j < PER; ++j) {
    bool p = key[j] < T;
    unsigned long long m = __ballot(p);
    if (p) candw[nlt + __popcll(m & lmask)] = key2f(key[j]);
    nlt += __popcll(m);
  }
  float tv = key2f(T);
  for (int i = nlt + lane; i < K_; i += 64) candw[i] = tv;
}

// ---- exact sum of 64 smallest among NP*64 candidates (one wave) ----
template <int NP>
__device__ __forceinline__ float final_sum(const float* __restrict__ cand,
                                           int lane) {
  float v[NP]; unsigned kk[NP];
#pragma unroll
  for (int j = 0; j < NP; ++j) {
    v[j] = cand[j * 64 + lane];
    kk[j] = f2key(v[j]);
  }
  unsigned T = bisect64<NP>(kk);
  float s = 0.f; int c = 0;
#pragma unroll
  for (int j = 0; j < NP; ++j)
    if (kk[j] < T) { s += v[j]; c++; }
#pragma unroll
  for (int off = 32; off > 0; off >>= 1) {
    s += __shfl_down(s, off);
    c += __shfl_down(c, off);
  }
  return s + (float)(K_ - c) * key2f(T);  // valid on lane 0
}

// ------- kernel 3: fused intra+inter select, 2 columns per block -------
// blocks 0..511: intra cols (2b, 2b+1); blocks 512..1023: inter cols.
// 1024 threads = 16 waves; batch-major row order keeps register pressure low;
// sched_barrier(0) per row stops load hoisting (the R4 spill cause).
__global__ __launch_bounds__(TSEL) void select_kernel(
    const float* __restrict__ outputs, const float* __restrict__ wsro,
    float* __restrict__ ws) {
  __shared__ float vsh[2][B_][D_];
  __shared__ float cvsh[2][B_];
  __shared__ float cand[2][TSEL];
  int tid = threadIdx.x, wave = tid >> 6, lane = tid & 63;
  int bid = blockIdx.x;
  int is_intra = bid < (N_ / 2);
  int c0 = (is_intra ? bid : bid - N_ / 2) * 2;
  if (tid < 2 * B_ * D_) {
    int c = tid / (B_ * D_), rem = tid % (B_ * D_), b = rem / D_, d = rem % D_;
    vsh[c][b][d] = outputs[(b * N_ + c0 + c) * D_ + d];
  }
  if (tid < 2 * B_) {
    int c = tid >> 2, b = tid & 3;
    cvsh[c][b] = wsro[WS_PPRE + (b * N_ + c0 + c) * PPRE_STRIDE + 10];
  }
  __syncthreads();

  if (is_intra) {
    constexpr int PER = BM_ / TSEL;  // 8 (2 rows per batch)
    unsigned k0[PER], k1[PER];
    const float* pre = wsro + WS_TPRE;
#pragma unroll
    for (int b = 0; b < B_; ++b) {
      float v0[D_], v1[D_];
#pragma unroll
      for (int d = 0; d < D_; ++d) { v0[d] = vsh[0][b][d]; v1[d] = vsh[1][b][d]; }
      float cv0 = cvsh[0][b], cv1 = cvsh[1][b];
#pragma unroll
      for (int jj = 0; jj < 2; ++jj) {
        int j = b * 2 + jj;                       // row i>>11 == b by construction
        const float* row = pre + (tid + TSEL * j) * TPRE_STRIDE;
        float4 a0 = *(const float4*)row;
        float4 a1 = *(const float4*)(row + 4);
        float2 a2 = *(const float2*)(row + 8);
        float d0 = a0.x * v0[0] + a0.y * v0[1] + a0.z * v0[2] + a0.w * v0[3] +
                   a1.x * v0[4] + a1.y * v0[5] + a1.z * v0[6] + a1.w * v0[7] +
                   a2.x * v0[8];
        float d1 = a0.x * v1[0] + a0.y * v1[1] + a0.z * v1[2] + a0.w * v1[3] +
                   a1.x * v1[4] + a1.y * v1[5] + a1.z * v1[6] + a1.w * v1[7] +
                   a2.x * v1[8];
        k0[j] = f2key(a2.y + cv0 - 2.0f * d0);
        k1[j] = f2key(a2.y + cv1 - 2.0f * d1);
        __builtin_amdgcn_sched_barrier(0);
      }
    }
    wave_top64<PER>(k0, &cand[0][wave * 64], lane);
    wave_top64<PER>(k1, &cand[1][wave * 64], lane);
  } else {
    constexpr int PER = BN_ / TSEL;  // 4 (1 row per batch)
    unsigned k0[PER], k1[PER];
    const float* pre = wsro + WS_PPRE;
#pragma unroll
    for (int b = 0; b < B_; ++b) {
      float v0[D_], v1[D_];
#pragma unroll
      for (int d = 0; d < D_; ++d) { v0[d] = vsh[0][b][d]; v1[d] = vsh[1][b][d]; }
      float cv0 = cvsh[0][b], cv1 = cvsh[1][b];
      const float* row = pre + (tid + TSEL * b) * PPRE_STRIDE;  // i>>10 == b
      float4 a0 = *(const float4*)row;
      float4 a1 = *(const float4*)(row + 4);
      float2 a2 = *(const float2*)(row + 8);
      float d0 = a0.x * v0[0] + a0.y * v0[1] + a0.z * v0[2] + a0.w * v0[3] +
                 a1.x * v0[4] + a1.y * v0[5] + a1.z * v0[6] + a1.w * v0[7] +
                 a2.x * v0[8];
      float d1 = a0.x * v1[0] + a0.y * v1[1] + a0.z * v1[2] + a0.w * v1[3] +
                 a1.x * v1[4] + a1.y * v1[5] + a1.z * v1[6] + a1.w * v1[7] +
                 a2.x * v1[8];
      k0[b] = f2key(a2.y + cv0 - 2.0f * d0);
      k1[b] = f2key(a2.y + cv1 - 2.0f * d1);
      __builtin_amdgcn_sched_barrier(0);
    }
    wave_top64<PER>(k0, &cand[0][wave * 64], lane);
    wave_top64<PER>(k1, &cand[1][wave * 64], lane);
  }
  __syncthreads();
  if (wave < 2) {
    float s = final_sum<TSEL / 64>(cand[wave], lane);
    if (lane == 0)
      ws[(is_intra ? WS_CS_INTRA : WS_CS_INTER) + c0 + wave] = s;
  }
}

// ---------------- kernel 4: final deterministic reduce ----------------
__global__ __launch_bounds__(256) void reduce_kernel(
    const float* __restrict__ ws, float* __restrict__ out) {
  __shared__ double sbuf[256];
  __shared__ double tA;
  int tid = threadIdx.x;
  double sa = 0.0, sb = 0.0;
  for (int i = tid; i < N_; i += 256) {
    sa += (double)ws[WS_CS_INTRA + i];
    sb += (double)ws[WS_CS_INTER + i];
  }
  sbuf[tid] = sa;
  __syncthreads();
  for (int off = 128; off > 0; off >>= 1) {
    if (tid < off) sbuf[tid] += sbuf[tid + off];
    __syncthreads();
  }
  if (tid == 0) tA = sbuf[0];
  __syncthreads();
  sbuf[tid] = sb;
  __syncthreads();
  for (int off = 128; off > 0; off >>= 1) {
    if (tid < off) sbuf[tid] += sbuf[tid + off];
    __syncthreads();
  }
  if (tid == 0) {
    double denom = (double)N_ * (double)K_;
    out[0] = (float)(tA / denom - 0.1 * (sbuf[0] / denom));
  }
}

extern "C" void kernel_launch(void* const* d_in, const int* in_sizes, int n_in,
                              void* d_out, int out_size, void* d_ws,
                              size_t ws_size, hipStream_t stream) {
  const float* outputs = (const float*)d_in[0];
  const float* targets = (const float*)d_in[1];
  const void* mask = d_in[2];
  float* ws = (float*)d_ws;

  hipLaunchKernelGGL(stats_part_kernel, dim3(NPART), dim3(256), 0, stream,
                     targets, mask, ws);
  hipLaunchKernelGGL(stats_fin_kernel, dim3(1), dim3(64), 0, stream, ws);
  hipLaunchKernelGGL(pre_kernel, dim3((BM_ + BN_ + 255) / 256), dim3(256), 0,
                     stream, outputs, targets, mask, ws);
  hipLaunchKernelGGL(select_kernel, dim3(N_), dim3(TSEL), 0, stream,
                     outputs, ws, ws);
  hipLaunchKernelGGL(reduce_kernel, dim3(1), dim3(256), 0, stream, ws,
                     (float*)d_out);
}

// Round 6
// 102.367 us; speedup vs baseline: 1.4507x; 1.4507x over previous
//
#include <hip/hip_runtime.h>
#include <math.h>

#define B_ 4
#define N_ 1024
#define M_ 2048
#define D_ 9
#define K_ 64
#define BM_ (B_*M_)   // 8192 targets
#define BN_ (B_*N_)   // 4096 preds
#define TPRE_STRIDE 12
#define PPRE_STRIDE 12
#define NPART 32      // stats partial blocks
#define NSTAT 55      // 1 + 9 + 45 accumulators
#define TSEL 512      // select kernel block size (8 waves)

// workspace layout (in floats)
#define WS_A 0                                   // 81: cov_inv (symmetric)
#define WS_MEAN 81                               // 9
#define WS_TPRE 96                               // 8192*12: [Au(9), uAu, pad, pad]
#define WS_PPRE (WS_TPRE + BM_*TPRE_STRIDE)      // 4096*12: [Aq(9), qAq, yAy, pad]
#define WS_CS_INTRA (WS_PPRE + BN_*PPRE_STRIDE)  // 1024 per-column sums
#define WS_CS_INTER (WS_CS_INTRA + N_)           // 1024
#define WS_PART (WS_CS_INTER + N_)               // 32*56 stats partials

__device__ __forceinline__ unsigned f2key(float f) {
  unsigned b = __float_as_uint(f);
  return (b & 0x80000000u) ? ~b : (b | 0x80000000u);
}
__device__ __forceinline__ float key2f(unsigned k) {
  unsigned b = (k & 0x80000000u) ? (k ^ 0x80000000u) : ~k;
  return __uint_as_float(b);
}

// mask dtype auto-detect from first 8192 bytes (always in-bounds for
// u8/i32/i64 layouts). 0 = u8/bool, 1 = int32, 2 = int64.
__device__ int detect_mask_fmt(const void* mask, int* flags /*shared[2]*/) {
  int tid = threadIdx.x;
  if (tid < 2) flags[tid] = 0;
  __syncthreads();
  const unsigned char* mb = (const unsigned char*)mask;
  int la = 0, lb = 0;
  for (int i = tid; i < BM_; i += blockDim.x) {
    unsigned char c = mb[i];
    if (c) { if (i & 3) la = 1; else if ((i & 7) == 4) lb = 1; }
  }
  if (la) atomicOr(&flags[0], 1);
  if (lb) atomicOr(&flags[1], 1);
  __syncthreads();
  return flags[0] ? 0 : (flags[1] ? 1 : 2);
}
__device__ __forceinline__ int mask_at(const void* mask, int fmt, int t) {
  if (fmt == 0) return ((const unsigned char*)mask)[t] != 0;
  if (fmt == 1) return ((const int*)mask)[t] != 0;
  return ((const long long*)mask)[t] != 0LL;
}

// -------- kernel 1a: per-block partial stats (S, Σt, Σ t tᵀ) in f32 --------
__global__ __launch_bounds__(256) void stats_part_kernel(
    const float* __restrict__ targets, const void* __restrict__ mask,
    float* __restrict__ ws) {
  __shared__ int flags[2];
  __shared__ float wpart[4][NSTAT];
  int tid = threadIdx.x;
  int fmt = detect_mask_fmt(mask, flags);
  int t = blockIdx.x * 256 + tid;  // one target per thread (BM_ = 32*256)

  float v[NSTAT];
  float tv[D_];
  int m = mask_at(mask, fmt, t);
  const float* tp = targets + t * D_;
#pragma unroll
  for (int d = 0; d < D_; ++d) tv[d] = m ? tp[d] : 0.f;
  v[0] = m ? 1.f : 0.f;
#pragma unroll
  for (int d = 0; d < D_; ++d) v[1 + d] = tv[d];
  {
    int p = 10;
#pragma unroll
    for (int i = 0; i < D_; ++i)
#pragma unroll
      for (int j = i; j < D_; ++j, ++p) v[p] = tv[i] * tv[j];
  }
#pragma unroll
  for (int off = 32; off > 0; off >>= 1)
#pragma unroll
    for (int p = 0; p < NSTAT; ++p) v[p] += __shfl_down(v[p], off);
  int wave = tid >> 6, lane = tid & 63;
  if (lane == 0)
#pragma unroll
    for (int p = 0; p < NSTAT; ++p) wpart[wave][p] = v[p];
  __syncthreads();
  if (tid < NSTAT) {
    float s = wpart[0][tid] + wpart[1][tid] + wpart[2][tid] + wpart[3][tid];
    ws[WS_PART + blockIdx.x * (NSTAT + 1) + tid] = s;
  }
}

// -------- kernel 1b: combine partials; lane-parallel f32 Gauss-Jordan --------
// Covariance is SPD (cond ~1 for standard-normal targets) -> no pivoting.
__global__ __launch_bounds__(64) void stats_fin_kernel(float* __restrict__ ws) {
  __shared__ float tot[NSTAT];
  __shared__ float Atmp[9][9];
  int lane = threadIdx.x;
  if (lane < NSTAT) {
    double s = 0.0;
    for (int b = 0; b < NPART; ++b)
      s += (double)ws[WS_PART + b * (NSTAT + 1) + lane];
    tot[lane] = (float)s;
  }
  __syncthreads();
  float S = tot[0];
  float col[9];
  int j = lane - 9;
  if (lane < 9) {
    float mj = tot[1 + lane] / S;
#pragma unroll
    for (int r = 0; r < 9; ++r) {
      float mr = tot[1 + r] / S;
      int i0 = r < lane ? r : lane;
      int j0 = r < lane ? lane : r;
      int p = i0 * 9 - (i0 * (i0 - 1)) / 2 + (j0 - i0);
      col[r] = (tot[10 + p] - S * mr * mj) / (S - 1.0f);
    }
  } else {
#pragma unroll
    for (int r = 0; r < 9; ++r) col[r] = (r == j) ? 1.f : 0.f;
  }
#pragma unroll
  for (int c = 0; c < 9; ++c) {
    float pv = __shfl(col[c], c);
    float inv = 1.f / pv;
    col[c] *= inv;
    float f[9];
#pragma unroll
    for (int r = 0; r < 9; ++r) f[r] = __shfl(col[r], c);
#pragma unroll
    for (int r = 0; r < 9; ++r)
      if (r != c) col[r] -= f[r] * col[c];
  }
  if (lane >= 9 && lane < 18) {
#pragma unroll
    for (int r = 0; r < 9; ++r) Atmp[r][j] = col[r];
  }
  __syncthreads();
  if (lane < 9) ws[WS_MEAN + lane] = tot[1 + lane] / S;
  for (int idx = lane; idx < 81; idx += 64) {
    int i0 = idx / 9, j0 = idx % 9;
    ws[WS_A + idx] = 0.5f * (Atmp[i0][j0] + Atmp[j0][i0]);
  }
}

// ---------------- kernel 2: precompute factored terms ----------------
__global__ __launch_bounds__(256) void pre_kernel(
    const float* __restrict__ outputs, const float* __restrict__ targets,
    const void* __restrict__ mask, float* __restrict__ ws) {
  __shared__ int flags[2];
  __shared__ float Ash[81];
  __shared__ float msh[D_];
  int tid = threadIdx.x;
  int fmt = detect_mask_fmt(mask, flags);
  if (tid < 81) Ash[tid] = ws[WS_A + tid];
  if (tid < D_) msh[tid] = ws[WS_MEAN + tid];
  __syncthreads();
  int idx = blockIdx.x * 256 + tid;
  if (idx < BM_) {
    const float* tp = targets + idx * D_;
    float u[D_];
#pragma unroll
    for (int d = 0; d < D_; ++d) u[d] = tp[d] - msh[d];
    float cu = 0.f; float au[D_];
#pragma unroll
    for (int i = 0; i < D_; ++i) {
      float s = 0.f;
#pragma unroll
      for (int j = 0; j < D_; ++j) s += Ash[i * D_ + j] * u[j];
      au[i] = s; cu += u[i] * s;
    }
    if (!mask_at(mask, fmt, idx)) cu = INFINITY;
    float* o = ws + WS_TPRE + idx * TPRE_STRIDE;
#pragma unroll
    for (int d = 0; d < D_; ++d) o[d] = au[d];
    o[9] = cu; o[10] = 0.f; o[11] = 0.f;
  } else if (idx < BM_ + BN_) {
    int r = idx - BM_;
    const float* yp = outputs + r * D_;
    float y[D_], q[D_], aq[D_];
#pragma unroll
    for (int d = 0; d < D_; ++d) { y[d] = yp[d]; q[d] = y[d] + msh[d]; }
    float cp = 0.f, cq = 0.f;
#pragma unroll
    for (int i = 0; i < D_; ++i) {
      float sy = 0.f, sq = 0.f;
#pragma unroll
      for (int j = 0; j < D_; ++j) {
        sy += Ash[i * D_ + j] * y[j];
        sq += Ash[i * D_ + j] * q[j];
      }
      cp += y[i] * sy;
      aq[i] = sq; cq += q[i] * sq;
    }
    float* o = ws + WS_PPRE + r * PPRE_STRIDE;
#pragma unroll
    for (int d = 0; d < D_; ++d) o[d] = aq[d];
    o[9] = cq; o[10] = cp; o[11] = 0.f;
  }
}

// ---- wave-uniform bisection for the exact K_-th smallest key; ballot-count,
// ---- zero barriers. Returns T (an existing key).
template <int PER>
__device__ __forceinline__ unsigned bisect64(const unsigned* key) {
  unsigned kmin = 0xFFFFFFFFu, kmax = 0u;
#pragma unroll
  for (int j = 0; j < PER; ++j) {
    kmin = key[j] < kmin ? key[j] : kmin;
    kmax = key[j] > kmax ? key[j] : kmax;
  }
#pragma unroll
  for (int off = 32; off > 0; off >>= 1) {
    unsigned a = (unsigned)__shfl_xor((int)kmin, off);
    unsigned b = (unsigned)__shfl_xor((int)kmax, off);
    kmin = a < kmin ? a : kmin;
    kmax = b > kmax ? b : kmax;
  }
  unsigned lo = kmin, hi = kmax;
  while (lo < hi) {  // wave-uniform
    unsigned mid = lo + ((hi - lo) >> 1);
    int cnt = 0;
#pragma unroll
    for (int j = 0; j < PER; ++j) cnt += __popcll(__ballot(key[j] <= mid));
    if (cnt >= K_) hi = mid; else lo = mid + 1;
  }
  return lo;
}

// ---- per-wave exact top-64 multiset -> 64-slot LDS region ----
template <int PER>
__device__ __forceinline__ void wave_top64(const unsigned* key,
                                           float* __restrict__ candw,
                                           int lane) {
  unsigned T = bisect64<PER>(key);
  unsigned long long lmask = (1ull << lane) - 1ull;
  int nlt = 0;
#pragma unroll
  for (int j = 0; j < PER; ++j) {
    bool p = key[j] < T;
    unsigned long long m = __ballot(p);
    if (p) candw[nlt + __popcll(m & lmask)] = key2f(key[j]);
    nlt += __popcll(m);
  }
  float tv = key2f(T);
  for (int i = nlt + lane; i < K_; i += 64) candw[i] = tv;
}

// ---- exact sum of 64 smallest among NP*64 candidates (one wave) ----
template <int NP>
__device__ __forceinline__ float final_sum(const float* __restrict__ cand,
                                           int lane) {
  float v[NP]; unsigned kk[NP];
#pragma unroll
  for (int j = 0; j < NP; ++j) {
    v[j] = cand[j * 64 + lane];
    kk[j] = f2key(v[j]);
  }
  unsigned T = bisect64<NP>(kk);
  float s = 0.f; int c = 0;
#pragma unroll
  for (int j = 0; j < NP; ++j)
    if (kk[j] < T) { s += v[j]; c++; }
#pragma unroll
  for (int off = 32; off > 0; off >>= 1) {
    s += __shfl_down(s, off);
    c += __shfl_down(c, off);
  }
  return s + (float)(K_ - c) * key2f(T);  // valid on lane 0
}

// ------- kernel 3: fused intra+inter select, ONE column per block -------
// blocks 0..N-1: intra col; blocks N..2N-1: inter col. R3's register shape
// (key[PER] flat loop, vsh via LDS) = proven 48-VGPR no-spill codegen; R4's
// wave-local ballot select (2 barriers total) replaces R3's 32-barrier bisect.
__global__ __launch_bounds__(TSEL) void select_kernel(
    const float* __restrict__ outputs, const float* __restrict__ wsro,
    float* __restrict__ ws) {
  __shared__ float vsh[B_][D_];
  __shared__ float cvsh[B_];
  __shared__ float cand[TSEL];
  int tid = threadIdx.x, wave = tid >> 6, lane = tid & 63;
  int bid = blockIdx.x;
  int is_intra = bid < N_;
  int col = is_intra ? bid : bid - N_;
  if (tid < B_ * D_) {
    int b = tid / D_, d = tid % D_;
    vsh[b][d] = outputs[(b * N_ + col) * D_ + d];
  }
  if (tid < B_) cvsh[tid] = wsro[WS_PPRE + (tid * N_ + col) * PPRE_STRIDE + 10];
  __syncthreads();
  if (is_intra) {
    constexpr int PER = BM_ / TSEL;  // 16
    unsigned key[PER];
    const float* pre = wsro + WS_TPRE;
#pragma unroll
    for (int j = 0; j < PER; ++j) {
      int i = tid + TSEL * j;
      int b = i >> 11;
      const float* row = pre + i * TPRE_STRIDE;
      float4 a0 = *(const float4*)row;
      float4 a1 = *(const float4*)(row + 4);
      float2 a2 = *(const float2*)(row + 8);
      float dot = a0.x * vsh[b][0] + a0.y * vsh[b][1] + a0.z * vsh[b][2] +
                  a0.w * vsh[b][3] + a1.x * vsh[b][4] + a1.y * vsh[b][5] +
                  a1.z * vsh[b][6] + a1.w * vsh[b][7] + a2.x * vsh[b][8];
      key[j] = f2key(a2.y + cvsh[b] - 2.0f * dot);
    }
    wave_top64<PER>(key, &cand[wave * 64], lane);
  } else {
    constexpr int PER = BN_ / TSEL;  // 8
    unsigned key[PER];
    const float* pre = wsro + WS_PPRE;
#pragma unroll
    for (int j = 0; j < PER; ++j) {
      int i = tid + TSEL * j;
      int b = i >> 10;
      const float* row = pre + i * PPRE_STRIDE;
      float4 a0 = *(const float4*)row;
      float4 a1 = *(const float4*)(row + 4);
      float2 a2 = *(const float2*)(row + 8);
      float dot = a0.x * vsh[b][0] + a0.y * vsh[b][1] + a0.z * vsh[b][2] +
                  a0.w * vsh[b][3] + a1.x * vsh[b][4] + a1.y * vsh[b][5] +
                  a1.z * vsh[b][6] + a1.w * vsh[b][7] + a2.x * vsh[b][8];
      key[j] = f2key(a2.y + cvsh[b] - 2.0f * dot);
    }
    wave_top64<PER>(key, &cand[wave * 64], lane);
  }
  __syncthreads();
  if (wave == 0) {
    float s = final_sum<TSEL / 64>(cand, lane);
    if (lane == 0)
      ws[(is_intra ? WS_CS_INTRA : WS_CS_INTER) + col] = s;
  }
}

// ---------------- kernel 4: final deterministic reduce ----------------
__global__ __launch_bounds__(256) void reduce_kernel(
    const float* __restrict__ ws, float* __restrict__ out) {
  __shared__ double sbuf[256];
  __shared__ double tA;
  int tid = threadIdx.x;
  double sa = 0.0, sb = 0.0;
  for (int i = tid; i < N_; i += 256) {
    sa += (double)ws[WS_CS_INTRA + i];
    sb += (double)ws[WS_CS_INTER + i];
  }
  sbuf[tid] = sa;
  __syncthreads();
  for (int off = 128; off > 0; off >>= 1) {
    if (tid < off) sbuf[tid] += sbuf[tid + off];
    __syncthreads();
  }
  if (tid == 0) tA = sbuf[0];
  __syncthreads();
  sbuf[tid] = sb;
  __syncthreads();
  for (int off = 128; off > 0; off >>= 1) {
    if (tid < off) sbuf[tid] += sbuf[tid + off];
    __syncthreads();
  }
  if (tid == 0) {
    double denom = (double)N_ * (double)K_;
    out[0] = (float)(tA / denom - 0.1 * (sbuf[0] / denom));
  }
}

extern "C" void kernel_launch(void* const* d_in, const int* in_sizes, int n_in,
                              void* d_out, int out_size, void* d_ws,
                              size_t ws_size, hipStream_t stream) {
  const float* outputs = (const float*)d_in[0];
  const float* targets = (const float*)d_in[1];
  const void* mask = d_in[2];
  float* ws = (float*)d_ws;

  hipLaunchKernelGGL(stats_part_kernel, dim3(NPART), dim3(256), 0, stream,
                     targets, mask, ws);
  hipLaunchKernelGGL(stats_fin_kernel, dim3(1), dim3(64), 0, stream, ws);
  hipLaunchKernelGGL(pre_kernel, dim3((BM_ + BN_ + 255) / 256), dim3(256), 0,
                     stream, outputs, targets, mask, ws);
  hipLaunchKernelGGL(select_kernel, dim3(2 * N_), dim3(TSEL), 0, stream,
                     outputs, ws, ws);
  hipLaunchKernelGGL(reduce_kernel, dim3(1), dim3(256), 0, stream, ws,
                     (float*)d_out);
}

// Round 7
// 83.722 us; speedup vs baseline: 1.7738x; 1.2227x over previous
//
#include <hip/hip_runtime.h>
#include <math.h>

#define B_ 4
#define N_ 1024
#define M_ 2048
#define D_ 9
#define K_ 64
#define BM_ (B_*M_)   // 8192 targets
#define BN_ (B_*N_)   // 4096 preds
#define TPRE_STRIDE 12
#define PPRE_STRIDE 12
#define NPART 32      // stats partial blocks
#define NSTAT 55      // 1 + 9 + 45 accumulators
#define TSEL 512      // select kernel block size (8 waves)

// workspace layout (in floats)
#define WS_A 0                                   // 81: cov_inv (symmetric)
#define WS_MEAN 81                               // 9
#define WS_TPRE 96                               // 8192*12: [Au(9), uAu, pad, pad]
#define WS_PPRE (WS_TPRE + BM_*TPRE_STRIDE)      // 4096*12: [Aq(9), qAq, yAy, pad]
#define WS_CS_INTRA (WS_PPRE + BN_*PPRE_STRIDE)  // 1024 per-column sums
#define WS_CS_INTER (WS_CS_INTRA + N_)           // 1024
#define WS_PART (WS_CS_INTER + N_)               // 32*56 stats partials
#define WS_CAND (WS_PART + NPART*(NSTAT+1))      // 2048 cols * 512 candidates

__device__ __forceinline__ unsigned f2key(float f) {
  unsigned b = __float_as_uint(f);
  return (b & 0x80000000u) ? ~b : (b | 0x80000000u);
}
__device__ __forceinline__ float key2f(unsigned k) {
  unsigned b = (k & 0x80000000u) ? (k ^ 0x80000000u) : ~k;
  return __uint_as_float(b);
}

// mask dtype auto-detect from first 8192 bytes (always in-bounds for
// u8/i32/i64 layouts). 0 = u8/bool, 1 = int32, 2 = int64.
__device__ int detect_mask_fmt(const void* mask, int* flags /*shared[2]*/) {
  int tid = threadIdx.x;
  if (tid < 2) flags[tid] = 0;
  __syncthreads();
  const unsigned char* mb = (const unsigned char*)mask;
  int la = 0, lb = 0;
  for (int i = tid; i < BM_; i += blockDim.x) {
    unsigned char c = mb[i];
    if (c) { if (i & 3) la = 1; else if ((i & 7) == 4) lb = 1; }
  }
  if (la) atomicOr(&flags[0], 1);
  if (lb) atomicOr(&flags[1], 1);
  __syncthreads();
  return flags[0] ? 0 : (flags[1] ? 1 : 2);
}
__device__ __forceinline__ int mask_at(const void* mask, int fmt, int t) {
  if (fmt == 0) return ((const unsigned char*)mask)[t] != 0;
  if (fmt == 1) return ((const int*)mask)[t] != 0;
  return ((const long long*)mask)[t] != 0LL;
}

// -------- kernel 1a: per-block partial stats (S, Σt, Σ t tᵀ) in f32 --------
__global__ __launch_bounds__(256) void stats_part_kernel(
    const float* __restrict__ targets, const void* __restrict__ mask,
    float* __restrict__ ws) {
  __shared__ int flags[2];
  __shared__ float wpart[4][NSTAT];
  int tid = threadIdx.x;
  int fmt = detect_mask_fmt(mask, flags);
  int t = blockIdx.x * 256 + tid;  // one target per thread (BM_ = 32*256)

  float v[NSTAT];
  float tv[D_];
  int m = mask_at(mask, fmt, t);
  const float* tp = targets + t * D_;
#pragma unroll
  for (int d = 0; d < D_; ++d) tv[d] = m ? tp[d] : 0.f;
  v[0] = m ? 1.f : 0.f;
#pragma unroll
  for (int d = 0; d < D_; ++d) v[1 + d] = tv[d];
  {
    int p = 10;
#pragma unroll
    for (int i = 0; i < D_; ++i)
#pragma unroll
      for (int j = i; j < D_; ++j, ++p) v[p] = tv[i] * tv[j];
  }
#pragma unroll
  for (int off = 32; off > 0; off >>= 1)
#pragma unroll
    for (int p = 0; p < NSTAT; ++p) v[p] += __shfl_down(v[p], off);
  int wave = tid >> 6, lane = tid & 63;
  if (lane == 0)
#pragma unroll
    for (int p = 0; p < NSTAT; ++p) wpart[wave][p] = v[p];
  __syncthreads();
  if (tid < NSTAT) {
    float s = wpart[0][tid] + wpart[1][tid] + wpart[2][tid] + wpart[3][tid];
    ws[WS_PART + blockIdx.x * (NSTAT + 1) + tid] = s;
  }
}

// -------- kernel 1b: combine partials; lane-parallel f32 Gauss-Jordan --------
// Covariance is SPD (cond ~1 for standard-normal targets) -> no pivoting.
__global__ __launch_bounds__(64) void stats_fin_kernel(float* __restrict__ ws) {
  __shared__ float tot[NSTAT];
  __shared__ float Atmp[9][9];
  int lane = threadIdx.x;
  if (lane < NSTAT) {
    double s = 0.0;
    for (int b = 0; b < NPART; ++b)
      s += (double)ws[WS_PART + b * (NSTAT + 1) + lane];
    tot[lane] = (float)s;
  }
  __syncthreads();
  float S = tot[0];
  float col[9];
  int j = lane - 9;
  if (lane < 9) {
    float mj = tot[1 + lane] / S;
#pragma unroll
    for (int r = 0; r < 9; ++r) {
      float mr = tot[1 + r] / S;
      int i0 = r < lane ? r : lane;
      int j0 = r < lane ? lane : r;
      int p = i0 * 9 - (i0 * (i0 - 1)) / 2 + (j0 - i0);
      col[r] = (tot[10 + p] - S * mr * mj) / (S - 1.0f);
    }
  } else {
#pragma unroll
    for (int r = 0; r < 9; ++r) col[r] = (r == j) ? 1.f : 0.f;
  }
#pragma unroll
  for (int c = 0; c < 9; ++c) {
    float pv = __shfl(col[c], c);
    float inv = 1.f / pv;
    col[c] *= inv;
    float f[9];
#pragma unroll
    for (int r = 0; r < 9; ++r) f[r] = __shfl(col[r], c);
#pragma unroll
    for (int r = 0; r < 9; ++r)
      if (r != c) col[r] -= f[r] * col[c];
  }
  if (lane >= 9 && lane < 18) {
#pragma unroll
    for (int r = 0; r < 9; ++r) Atmp[r][j] = col[r];
  }
  __syncthreads();
  if (lane < 9) ws[WS_MEAN + lane] = tot[1 + lane] / S;
  for (int idx = lane; idx < 81; idx += 64) {
    int i0 = idx / 9, j0 = idx % 9;
    ws[WS_A + idx] = 0.5f * (Atmp[i0][j0] + Atmp[j0][i0]);
  }
}

// ---------------- kernel 2: precompute factored terms ----------------
__global__ __launch_bounds__(256) void pre_kernel(
    const float* __restrict__ outputs, const float* __restrict__ targets,
    const void* __restrict__ mask, float* __restrict__ ws) {
  __shared__ int flags[2];
  __shared__ float Ash[81];
  __shared__ float msh[D_];
  int tid = threadIdx.x;
  int fmt = detect_mask_fmt(mask, flags);
  if (tid < 81) Ash[tid] = ws[WS_A + tid];
  if (tid < D_) msh[tid] = ws[WS_MEAN + tid];
  __syncthreads();
  int idx = blockIdx.x * 256 + tid;
  if (idx < BM_) {
    const float* tp = targets + idx * D_;
    float u[D_];
#pragma unroll
    for (int d = 0; d < D_; ++d) u[d] = tp[d] - msh[d];
    float cu = 0.f; float au[D_];
#pragma unroll
    for (int i = 0; i < D_; ++i) {
      float s = 0.f;
#pragma unroll
      for (int j = 0; j < D_; ++j) s += Ash[i * D_ + j] * u[j];
      au[i] = s; cu += u[i] * s;
    }
    if (!mask_at(mask, fmt, idx)) cu = INFINITY;
    float* o = ws + WS_TPRE + idx * TPRE_STRIDE;
#pragma unroll
    for (int d = 0; d < D_; ++d) o[d] = au[d];
    o[9] = cu; o[10] = 0.f; o[11] = 0.f;
  } else if (idx < BM_ + BN_) {
    int r = idx - BM_;
    const float* yp = outputs + r * D_;
    float y[D_], q[D_], aq[D_];
#pragma unroll
    for (int d = 0; d < D_; ++d) { y[d] = yp[d]; q[d] = y[d] + msh[d]; }
    float cp = 0.f, cq = 0.f;
#pragma unroll
    for (int i = 0; i < D_; ++i) {
      float sy = 0.f, sq = 0.f;
#pragma unroll
      for (int j = 0; j < D_; ++j) {
        sy += Ash[i * D_ + j] * y[j];
        sq += Ash[i * D_ + j] * q[j];
      }
      cp += y[i] * sy;
      aq[i] = sq; cq += q[i] * sq;
    }
    float* o = ws + WS_PPRE + r * PPRE_STRIDE;
#pragma unroll
    for (int d = 0; d < D_; ++d) o[d] = aq[d];
    o[9] = cq; o[10] = cp; o[11] = 0.f;
  }
}

// ---- wave-uniform bisection for the exact K_-th smallest key; ballot-count,
// ---- zero barriers. Tight bounds: lo = global min; hi = max of per-lane
// ---- minima (each lane owns a key <= hi, so count(<=hi) >= 64 >= K_).
template <int PER>
__device__ __forceinline__ unsigned bisect64(const unsigned* key) {
  unsigned kmin = 0xFFFFFFFFu;
#pragma unroll
  for (int j = 0; j < PER; ++j) kmin = key[j] < kmin ? key[j] : kmin;
  unsigned gmin = kmin, mmax = kmin;
#pragma unroll
  for (int off = 32; off > 0; off >>= 1) {
    unsigned a = (unsigned)__shfl_xor((int)gmin, off);
    unsigned b = (unsigned)__shfl_xor((int)mmax, off);
    gmin = a < gmin ? a : gmin;
    mmax = b > mmax ? b : mmax;
  }
  unsigned lo = gmin, hi = mmax;
  while (lo < hi) {  // wave-uniform
    unsigned mid = lo + ((hi - lo) >> 1);
    int cnt = 0;
#pragma unroll
    for (int j = 0; j < PER; ++j) cnt += __popcll(__ballot(key[j] <= mid));
    if (cnt >= K_) hi = mid; else lo = mid + 1;
  }
  return lo;
}

// ---- per-wave exact top-64 multiset -> 64-slot region (LDS or global) ----
template <int PER>
__device__ __forceinline__ void wave_top64(const unsigned* key,
                                           float* candw, int lane) {
  unsigned T = bisect64<PER>(key);
  unsigned long long lmask = (1ull << lane) - 1ull;
  int nlt = 0;
#pragma unroll
  for (int j = 0; j < PER; ++j) {
    bool p = key[j] < T;
    unsigned long long m = __ballot(p);
    if (p) candw[nlt + __popcll(m & lmask)] = key2f(key[j]);
    nlt += __popcll(m);
  }
  float tv = key2f(T);
  for (int i = nlt + lane; i < K_; i += 64) candw[i] = tv;
}

// ---- exact sum of 64 smallest among NP*64 candidates (one wave) ----
template <int NP>
__device__ __forceinline__ float final_sum(const float* __restrict__ cand,
                                           int lane) {
  float v[NP]; unsigned kk[NP];
#pragma unroll
  for (int j = 0; j < NP; ++j) {
    v[j] = cand[j * 64 + lane];
    kk[j] = f2key(v[j]);
  }
  unsigned T = bisect64<NP>(kk);
  float s = 0.f; int c = 0;
#pragma unroll
  for (int j = 0; j < NP; ++j)
    if (kk[j] < T) { s += v[j]; c++; }
#pragma unroll
  for (int off = 32; off > 0; off >>= 1) {
    s += __shfl_down(s, off);
    c += __shfl_down(c, off);
  }
  return s + (float)(K_ - c) * key2f(T);  // valid on lane 0
}

// ------- kernel 3: fused intra+inter select, ONE column per block -------
// Per-batch register-resident column vector (b is compile-time per row group),
// per-wave ballot top-64 straight to global candidates, NO trailing barrier —
// waves retire independently. sched_barrier bounds load hoisting per batch.
__global__ __launch_bounds__(TSEL) void select_kernel(
    const float* __restrict__ outputs, const float* __restrict__ wsro,
    float* __restrict__ cand_out) {
  __shared__ float vsh[B_][D_];
  __shared__ float cvsh[B_];
  int tid = threadIdx.x, wave = tid >> 6, lane = tid & 63;
  int bid = blockIdx.x;
  int is_intra = bid < N_;
  int col = is_intra ? bid : bid - N_;
  if (tid < B_ * D_) {
    int b = tid / D_, d = tid % D_;
    vsh[b][d] = outputs[(b * N_ + col) * D_ + d];
  }
  if (tid < B_) cvsh[tid] = wsro[WS_PPRE + (tid * N_ + col) * PPRE_STRIDE + 10];
  __syncthreads();
  float* candw = cand_out + (bid * 8 + wave) * 64;
  if (is_intra) {
    constexpr int PER = BM_ / TSEL;  // 16 (4 rows per batch)
    unsigned key[PER];
    const float* pre = wsro + WS_TPRE;
#pragma unroll
    for (int bb = 0; bb < B_; ++bb) {
      float v[D_];
#pragma unroll
      for (int d = 0; d < D_; ++d) v[d] = vsh[bb][d];
      float cv = cvsh[bb];
#pragma unroll
      for (int jj = 0; jj < 4; ++jj) {
        int j = bb * 4 + jj;  // i>>11 == bb for i = tid + 512*j
        const float* row = pre + (tid + TSEL * j) * TPRE_STRIDE;
        float4 a0 = *(const float4*)row;
        float4 a1 = *(const float4*)(row + 4);
        float2 a2 = *(const float2*)(row + 8);
        float dot = a0.x * v[0] + a0.y * v[1] + a0.z * v[2] + a0.w * v[3] +
                    a1.x * v[4] + a1.y * v[5] + a1.z * v[6] + a1.w * v[7] +
                    a2.x * v[8];
        key[j] = f2key(a2.y + cv - 2.0f * dot);
      }
      __builtin_amdgcn_sched_barrier(0);
    }
    wave_top64<PER>(key, candw, lane);
  } else {
    constexpr int PER = BN_ / TSEL;  // 8 (2 rows per batch)
    unsigned key[PER];
    const float* pre = wsro + WS_PPRE;
#pragma unroll
    for (int bb = 0; bb < B_; ++bb) {
      float v[D_];
#pragma unroll
      for (int d = 0; d < D_; ++d) v[d] = vsh[bb][d];
      float cv = cvsh[bb];
#pragma unroll
      for (int jj = 0; jj < 2; ++jj) {
        int j = bb * 2 + jj;  // i>>10 == bb for i = tid + 512*j
        const float* row = pre + (tid + TSEL * j) * PPRE_STRIDE;
        float4 a0 = *(const float4*)row;
        float4 a1 = *(const float4*)(row + 4);
        float2 a2 = *(const float2*)(row + 8);
        float dot = a0.x * v[0] + a0.y * v[1] + a0.z * v[2] + a0.w * v[3] +
                    a1.x * v[4] + a1.y * v[5] + a1.z * v[6] + a1.w * v[7] +
                    a2.x * v[8];
        key[j] = f2key(a2.y + cv - 2.0f * dot);
      }
      __builtin_amdgcn_sched_barrier(0);
    }
    wave_top64<PER>(key, candw, lane);
  }
}

// ------- kernel 3b: merge 512 candidates/column -> exact top-64 sum -------
// One wave per column; 2048 waves = 256 blocks x 512 threads.
__global__ __launch_bounds__(512) void merge_kernel(
    const float* __restrict__ cand, float* __restrict__ ws) {
  int gw = (blockIdx.x * 512 + threadIdx.x) >> 6;  // global wave = column id
  int lane = threadIdx.x & 63;
  float s = final_sum<8>(cand + gw * 512, lane);
  if (lane == 0) {
    int is_intra = gw < N_;
    int col = is_intra ? gw : gw - N_;
    ws[(is_intra ? WS_CS_INTRA : WS_CS_INTER) + col] = s;
  }
}

// ---------------- kernel 4: final deterministic reduce ----------------
__global__ __launch_bounds__(256) void reduce_kernel(
    const float* __restrict__ ws, float* __restrict__ out) {
  __shared__ double sbuf[256];
  __shared__ double tA;
  int tid = threadIdx.x;
  double sa = 0.0, sb = 0.0;
  for (int i = tid; i < N_; i += 256) {
    sa += (double)ws[WS_CS_INTRA + i];
    sb += (double)ws[WS_CS_INTER + i];
  }
  sbuf[tid] = sa;
  __syncthreads();
  for (int off = 128; off > 0; off >>= 1) {
    if (tid < off) sbuf[tid] += sbuf[tid + off];
    __syncthreads();
  }
  if (tid == 0) tA = sbuf[0];
  __syncthreads();
  sbuf[tid] = sb;
  __syncthreads();
  for (int off = 128; off > 0; off >>= 1) {
    if (tid < off) sbuf[tid] += sbuf[tid + off];
    __syncthreads();
  }
  if (tid == 0) {
    double denom = (double)N_ * (double)K_;
    out[0] = (float)(tA / denom - 0.1 * (sbuf[0] / denom));
  }
}

extern "C" void kernel_launch(void* const* d_in, const int* in_sizes, int n_in,
                              void* d_out, int out_size, void* d_ws,
                              size_t ws_size, hipStream_t stream) {
  const float* outputs = (const float*)d_in[0];
  const float* targets = (const float*)d_in[1];
  const void* mask = d_in[2];
  float* ws = (float*)d_ws;

  hipLaunchKernelGGL(stats_part_kernel, dim3(NPART), dim3(256), 0, stream,
                     targets, mask, ws);
  hipLaunchKernelGGL(stats_fin_kernel, dim3(1), dim3(64), 0, stream, ws);
  hipLaunchKernelGGL(pre_kernel, dim3((BM_ + BN_ + 255) / 256), dim3(256), 0,
                     stream, outputs, targets, mask, ws);
  hipLaunchKernelGGL(select_kernel, dim3(2 * N_), dim3(TSEL), 0, stream,
                     outputs, ws, ws + WS_CAND);
  hipLaunchKernelGGL(merge_kernel, dim3(2 * N_ / 8), dim3(512), 0, stream,
                     ws + WS_CAND, ws);
  hipLaunchKernelGGL(reduce_kernel, dim3(1), dim3(256), 0, stream, ws,
                     (float*)d_out);
}

// Round 8
// 75.844 us; speedup vs baseline: 1.9580x; 1.1039x over previous
//
#include <hip/hip_runtime.h>
#include <math.h>

#define B_ 4
#define N_ 1024
#define M_ 2048
#define D_ 9
#define K_ 64
#define BM_ (B_*M_)   // 8192 targets
#define BN_ (B_*N_)   // 4096 preds
#define TPRE_STRIDE 12
#define PPRE_STRIDE 12
#define NPART 32      // stats partial blocks
#define NSTAT 55      // 1 + 9 + 45 accumulators
#define TSEL 512      // select kernel block size (8 waves)

// workspace layout (in floats)
#define WS_A 0                                   // 81: cov_inv (symmetric)
#define WS_MEAN 81                               // 9
#define WS_TPRE 96                               // 8192*12: [Au(9), uAu, pad, pad]
#define WS_PPRE (WS_TPRE + BM_*TPRE_STRIDE)      // 4096*12: [Aq(9), qAq, yAy, pad]
#define WS_CS_INTRA (WS_PPRE + BN_*PPRE_STRIDE)  // 1024 per-column sums
#define WS_CS_INTER (WS_CS_INTRA + N_)           // 1024
#define WS_PART (WS_CS_INTER + N_)               // 32*56 stats partials
#define WS_CANDI (WS_PART + NPART*(NSTAT+1))     // intra cands: 1024 cols * 1024
#define WS_CANDE (WS_CANDI + 1024*1024)          // inter cands: 1024 cols * 512

__device__ __forceinline__ unsigned f2key(float f) {
  unsigned b = __float_as_uint(f);
  return (b & 0x80000000u) ? ~b : (b | 0x80000000u);
}
__device__ __forceinline__ float key2f(unsigned k) {
  unsigned b = (k & 0x80000000u) ? (k ^ 0x80000000u) : ~k;
  return __uint_as_float(b);
}

// mask dtype auto-detect from first 8192 bytes. 0=u8/bool, 1=int32, 2=int64.
__device__ int detect_mask_fmt(const void* mask, int* flags /*shared[2]*/) {
  int tid = threadIdx.x;
  if (tid < 2) flags[tid] = 0;
  __syncthreads();
  const unsigned char* mb = (const unsigned char*)mask;
  int la = 0, lb = 0;
  for (int i = tid; i < BM_; i += blockDim.x) {
    unsigned char c = mb[i];
    if (c) { if (i & 3) la = 1; else if ((i & 7) == 4) lb = 1; }
  }
  if (la) atomicOr(&flags[0], 1);
  if (lb) atomicOr(&flags[1], 1);
  __syncthreads();
  return flags[0] ? 0 : (flags[1] ? 1 : 2);
}
__device__ __forceinline__ int mask_at(const void* mask, int fmt, int t) {
  if (fmt == 0) return ((const unsigned char*)mask)[t] != 0;
  if (fmt == 1) return ((const int*)mask)[t] != 0;
  return ((const long long*)mask)[t] != 0LL;
}

// -------- kernel 1a: per-block partial stats (S, Σt, Σ t tᵀ) in f32 --------
__global__ __launch_bounds__(256) void stats_part_kernel(
    const float* __restrict__ targets, const void* __restrict__ mask,
    float* __restrict__ ws) {
  __shared__ int flags[2];
  __shared__ float wpart[4][NSTAT];
  int tid = threadIdx.x;
  int fmt = detect_mask_fmt(mask, flags);
  int t = blockIdx.x * 256 + tid;  // one target per thread (BM_ = 32*256)

  float v[NSTAT];
  float tv[D_];
  int m = mask_at(mask, fmt, t);
  const float* tp = targets + t * D_;
#pragma unroll
  for (int d = 0; d < D_; ++d) tv[d] = m ? tp[d] : 0.f;
  v[0] = m ? 1.f : 0.f;
#pragma unroll
  for (int d = 0; d < D_; ++d) v[1 + d] = tv[d];
  {
    int p = 10;
#pragma unroll
    for (int i = 0; i < D_; ++i)
#pragma unroll
      for (int j = i; j < D_; ++j, ++p) v[p] = tv[i] * tv[j];
  }
#pragma unroll
  for (int off = 32; off > 0; off >>= 1)
#pragma unroll
    for (int p = 0; p < NSTAT; ++p) v[p] += __shfl_down(v[p], off);
  int wave = tid >> 6, lane = tid & 63;
  if (lane == 0)
#pragma unroll
    for (int p = 0; p < NSTAT; ++p) wpart[wave][p] = v[p];
  __syncthreads();
  if (tid < NSTAT) {
    float s = wpart[0][tid] + wpart[1][tid] + wpart[2][tid] + wpart[3][tid];
    ws[WS_PART + blockIdx.x * (NSTAT + 1) + tid] = s;
  }
}

// -------- kernel 1b: combine partials; lane-parallel f32 Gauss-Jordan --------
__global__ __launch_bounds__(64) void stats_fin_kernel(float* __restrict__ ws) {
  __shared__ float tot[NSTAT];
  __shared__ float Atmp[9][9];
  int lane = threadIdx.x;
  if (lane < NSTAT) {
    double s = 0.0;
    for (int b = 0; b < NPART; ++b)
      s += (double)ws[WS_PART + b * (NSTAT + 1) + lane];
    tot[lane] = (float)s;
  }
  __syncthreads();
  float S = tot[0];
  float col[9];
  int j = lane - 9;
  if (lane < 9) {
    float mj = tot[1 + lane] / S;
#pragma unroll
    for (int r = 0; r < 9; ++r) {
      float mr = tot[1 + r] / S;
      int i0 = r < lane ? r : lane;
      int j0 = r < lane ? lane : r;
      int p = i0 * 9 - (i0 * (i0 - 1)) / 2 + (j0 - i0);
      col[r] = (tot[10 + p] - S * mr * mj) / (S - 1.0f);
    }
  } else {
#pragma unroll
    for (int r = 0; r < 9; ++r) col[r] = (r == j) ? 1.f : 0.f;
  }
#pragma unroll
  for (int c = 0; c < 9; ++c) {
    float pv = __shfl(col[c], c);
    float inv = 1.f / pv;
    col[c] *= inv;
    float f[9];
#pragma unroll
    for (int r = 0; r < 9; ++r) f[r] = __shfl(col[r], c);
#pragma unroll
    for (int r = 0; r < 9; ++r)
      if (r != c) col[r] -= f[r] * col[c];
  }
  if (lane >= 9 && lane < 18) {
#pragma unroll
    for (int r = 0; r < 9; ++r) Atmp[r][j] = col[r];
  }
  __syncthreads();
  if (lane < 9) ws[WS_MEAN + lane] = tot[1 + lane] / S;
  for (int idx = lane; idx < 81; idx += 64) {
    int i0 = idx / 9, j0 = idx % 9;
    ws[WS_A + idx] = 0.5f * (Atmp[i0][j0] + Atmp[j0][i0]);
  }
}

// ---------------- kernel 2: precompute factored terms ----------------
__global__ __launch_bounds__(256) void pre_kernel(
    const float* __restrict__ outputs, const float* __restrict__ targets,
    const void* __restrict__ mask, float* __restrict__ ws) {
  __shared__ int flags[2];
  __shared__ float Ash[81];
  __shared__ float msh[D_];
  int tid = threadIdx.x;
  int fmt = detect_mask_fmt(mask, flags);
  if (tid < 81) Ash[tid] = ws[WS_A + tid];
  if (tid < D_) msh[tid] = ws[WS_MEAN + tid];
  __syncthreads();
  int idx = blockIdx.x * 256 + tid;
  if (idx < BM_) {
    const float* tp = targets + idx * D_;
    float u[D_];
#pragma unroll
    for (int d = 0; d < D_; ++d) u[d] = tp[d] - msh[d];
    float cu = 0.f; float au[D_];
#pragma unroll
    for (int i = 0; i < D_; ++i) {
      float s = 0.f;
#pragma unroll
      for (int j = 0; j < D_; ++j) s += Ash[i * D_ + j] * u[j];
      au[i] = s; cu += u[i] * s;
    }
    if (!mask_at(mask, fmt, idx)) cu = INFINITY;
    float* o = ws + WS_TPRE + idx * TPRE_STRIDE;
#pragma unroll
    for (int d = 0; d < D_; ++d) o[d] = au[d];
    o[9] = cu; o[10] = 0.f; o[11] = 0.f;
  } else if (idx < BM_ + BN_) {
    int r = idx - BM_;
    const float* yp = outputs + r * D_;
    float y[D_], q[D_], aq[D_];
#pragma unroll
    for (int d = 0; d < D_; ++d) { y[d] = yp[d]; q[d] = y[d] + msh[d]; }
    float cp = 0.f, cq = 0.f;
#pragma unroll
    for (int i = 0; i < D_; ++i) {
      float sy = 0.f, sq = 0.f;
#pragma unroll
      for (int j = 0; j < D_; ++j) {
        sy += Ash[i * D_ + j] * y[j];
        sq += Ash[i * D_ + j] * q[j];
      }
      cp += y[i] * sy;
      aq[i] = sq; cq += q[i] * sq;
    }
    float* o = ws + WS_PPRE + r * PPRE_STRIDE;
#pragma unroll
    for (int d = 0; d < D_; ++d) o[d] = aq[d];
    o[9] = cq; o[10] = cp; o[11] = 0.f;
  }
}

// ---- single-chain bisect (used by merge). lo=global min; hi=max of per-lane
// ---- minima (each lane owns a key <= hi -> count(<=hi) >= 64 >= K_).
template <int PER>
__device__ __forceinline__ unsigned bisect64(const unsigned* key) {
  unsigned kmin = 0xFFFFFFFFu;
#pragma unroll
  for (int j = 0; j < PER; ++j) kmin = key[j] < kmin ? key[j] : kmin;
  unsigned gmin = kmin, mmax = kmin;
#pragma unroll
  for (int off = 32; off > 0; off >>= 1) {
    unsigned a = (unsigned)__shfl_xor((int)gmin, off);
    unsigned b = (unsigned)__shfl_xor((int)mmax, off);
    gmin = a < gmin ? a : gmin;
    mmax = b > mmax ? b : mmax;
  }
  unsigned lo = gmin, hi = mmax;
  while (lo < hi) {
    unsigned mid = lo + ((hi - lo) >> 1);
    int cnt = 0;
#pragma unroll
    for (int j = 0; j < PER; ++j) cnt += __popcll(__ballot(key[j] <= mid));
    if (cnt >= K_) hi = mid; else lo = mid + 1;
  }
  return lo;
}

// ---- fused DUAL bisect: two independent chains, one loop -> ILP on the
// ---- serial cmp->ballot->popc->update latency chain.
template <int PER>
__device__ __forceinline__ void bisect64x2(const unsigned* k0,
                                           const unsigned* k1,
                                           unsigned& T0, unsigned& T1) {
  unsigned mn0 = 0xFFFFFFFFu, mn1 = 0xFFFFFFFFu;
#pragma unroll
  for (int j = 0; j < PER; ++j) {
    mn0 = k0[j] < mn0 ? k0[j] : mn0;
    mn1 = k1[j] < mn1 ? k1[j] : mn1;
  }
  unsigned g0 = mn0, x0 = mn0, g1 = mn1, x1 = mn1;
#pragma unroll
  for (int off = 32; off > 0; off >>= 1) {
    unsigned a0 = (unsigned)__shfl_xor((int)g0, off);
    unsigned b0 = (unsigned)__shfl_xor((int)x0, off);
    unsigned a1 = (unsigned)__shfl_xor((int)g1, off);
    unsigned b1 = (unsigned)__shfl_xor((int)x1, off);
    g0 = a0 < g0 ? a0 : g0;  x0 = b0 > x0 ? b0 : x0;
    g1 = a1 < g1 ? a1 : g1;  x1 = b1 > x1 ? b1 : x1;
  }
  unsigned lo0 = g0, hi0 = x0, lo1 = g1, hi1 = x1;
  while ((lo0 < hi0) || (lo1 < hi1)) {  // wave-uniform
    unsigned mid0 = lo0 + ((hi0 - lo0) >> 1);
    unsigned mid1 = lo1 + ((hi1 - lo1) >> 1);
    int c0 = 0, c1 = 0;
#pragma unroll
    for (int j = 0; j < PER; ++j) {
      c0 += __popcll(__ballot(k0[j] <= mid0));
      c1 += __popcll(__ballot(k1[j] <= mid1));
    }
    if (lo0 < hi0) { if (c0 >= K_) hi0 = mid0; else lo0 = mid0 + 1; }
    if (lo1 < hi1) { if (c1 >= K_) hi1 = mid1; else lo1 = mid1 + 1; }
  }
  T0 = lo0; T1 = lo1;
}

// ---- compact keys < T into 64-slot region, pad with T ----
template <int PER>
__device__ __forceinline__ void compact64(const unsigned* key, unsigned T,
                                          float* candw, int lane) {
  unsigned long long lmask = (1ull << lane) - 1ull;
  int nlt = 0;
#pragma unroll
  for (int j = 0; j < PER; ++j) {
    bool p = key[j] < T;
    unsigned long long m = __ballot(p);
    if (p) candw[nlt + __popcll(m & lmask)] = key2f(key[j]);
    nlt += __popcll(m);
  }
  float tv = key2f(T);
  for (int i = nlt + lane; i < K_; i += 64) candw[i] = tv;
}

// ---- exact sum of 64 smallest among NP*64 candidates (one wave) ----
template <int NP>
__device__ __forceinline__ float final_sum(const float* __restrict__ cand,
                                           int lane) {
  float v[NP]; unsigned kk[NP];
#pragma unroll
  for (int j = 0; j < NP; ++j) {
    v[j] = cand[j * 64 + lane];
    kk[j] = f2key(v[j]);
  }
  unsigned T = bisect64<NP>(kk);
  float s = 0.f; int c = 0;
#pragma unroll
  for (int j = 0; j < NP; ++j)
    if (kk[j] < T) { s += v[j]; c++; }
#pragma unroll
  for (int off = 32; off > 0; off >>= 1) {
    s += __shfl_down(s, off);
    c += __shfl_down(c, off);
  }
  return s + (float)(K_ - c) * key2f(T);  // valid on lane 0
}

// ------- kernel 3: dual-column select -------
// bid<1024: intra pair p=bid>>1, half h=bid&1, cols {2p,2p+1}, rows [h*4096,+4096)
// bid>=1024: inter pair p=bid-1024, cols {2p,2p+1}, all 4096 rows.
// 16 key regs/thread (proven no-spill budget); fused dual bisect; no trailing
// barrier — waves write their 64 candidates to global and retire.
__global__ __launch_bounds__(TSEL) void select_kernel(
    const float* __restrict__ outputs, const float* __restrict__ wsro,
    float* __restrict__ ws) {
  __shared__ float vsh[2][B_][D_];
  __shared__ float cvsh[2][B_];
  int tid = threadIdx.x, wave = tid >> 6, lane = tid & 63;
  int bid = blockIdx.x;
  int is_intra = bid < N_;
  int p = is_intra ? (bid >> 1) : (bid - N_);
  int h = is_intra ? (bid & 1) : 0;
  int c0 = 2 * p;
  if (tid < 2 * B_ * D_) {
    int c = tid / (B_ * D_), rem = tid % (B_ * D_), b = rem / D_, d = rem % D_;
    vsh[c][b][d] = outputs[(b * N_ + c0 + c) * D_ + d];
  }
  if (tid < 2 * B_) {
    int c = tid >> 2, b = tid & 3;
    cvsh[c][b] = wsro[WS_PPRE + (b * N_ + c0 + c) * PPRE_STRIDE + 10];
  }
  __syncthreads();
  constexpr int PER = 8;
  unsigned k0[PER], k1[PER];
  if (is_intra) {
    const float* pre = wsro + WS_TPRE;
    int rowbase = h * 4096;
#pragma unroll
    for (int bbb = 0; bbb < 2; ++bbb) {
      int b = 2 * h + bbb;  // wave-uniform
      float v0[D_], v1[D_];
#pragma unroll
      for (int d = 0; d < D_; ++d) { v0[d] = vsh[0][b][d]; v1[d] = vsh[1][b][d]; }
      float cv0 = cvsh[0][b], cv1 = cvsh[1][b];
#pragma unroll
      for (int jj = 0; jj < 4; ++jj) {
        int j = bbb * 4 + jj;  // (rowbase+tid+512j)>>11 == b
        const float* row = pre + (rowbase + tid + TSEL * j) * TPRE_STRIDE;
        float4 a0 = *(const float4*)row;
        float4 a1 = *(const float4*)(row + 4);
        float2 a2 = *(const float2*)(row + 8);
        float d0 = a0.x * v0[0] + a0.y * v0[1] + a0.z * v0[2] + a0.w * v0[3] +
                   a1.x * v0[4] + a1.y * v0[5] + a1.z * v0[6] + a1.w * v0[7] +
                   a2.x * v0[8];
        float d1 = a0.x * v1[0] + a0.y * v1[1] + a0.z * v1[2] + a0.w * v1[3] +
                   a1.x * v1[4] + a1.y * v1[5] + a1.z * v1[6] + a1.w * v1[7] +
                   a2.x * v1[8];
        k0[j] = f2key(a2.y + cv0 - 2.0f * d0);
        k1[j] = f2key(a2.y + cv1 - 2.0f * d1);
      }
      __builtin_amdgcn_sched_barrier(0);
    }
  } else {
    const float* pre = wsro + WS_PPRE;
#pragma unroll
    for (int bb = 0; bb < B_; ++bb) {
      float v0[D_], v1[D_];
#pragma unroll
      for (int d = 0; d < D_; ++d) { v0[d] = vsh[0][bb][d]; v1[d] = vsh[1][bb][d]; }
      float cv0 = cvsh[0][bb], cv1 = cvsh[1][bb];
#pragma unroll
      for (int jj = 0; jj < 2; ++jj) {
        int j = bb * 2 + jj;  // (tid+512j)>>10 == bb
        const float* row = pre + (tid + TSEL * j) * PPRE_STRIDE;
        float4 a0 = *(const float4*)row;
        float4 a1 = *(const float4*)(row + 4);
        float2 a2 = *(const float2*)(row + 8);
        float d0 = a0.x * v0[0] + a0.y * v0[1] + a0.z * v0[2] + a0.w * v0[3] +
                   a1.x * v0[4] + a1.y * v0[5] + a1.z * v0[6] + a1.w * v0[7] +
                   a2.x * v0[8];
        float d1 = a0.x * v1[0] + a0.y * v1[1] + a0.z * v1[2] + a0.w * v1[3] +
                   a1.x * v1[4] + a1.y * v1[5] + a1.z * v1[6] + a1.w * v1[7] +
                   a2.x * v1[8];
        k0[j] = f2key(a2.y + cv0 - 2.0f * d0);
        k1[j] = f2key(a2.y + cv1 - 2.0f * d1);
      }
      __builtin_amdgcn_sched_barrier(0);
    }
  }
  unsigned T0, T1;
  bisect64x2<PER>(k0, k1, T0, T1);
  if (is_intra) {
    float* base0 = ws + WS_CANDI + (c0) * 1024 + h * 512 + wave * 64;
    float* base1 = ws + WS_CANDI + (c0 + 1) * 1024 + h * 512 + wave * 64;
    compact64<PER>(k0, T0, base0, lane);
    compact64<PER>(k1, T1, base1, lane);
  } else {
    float* base0 = ws + WS_CANDE + (c0) * 512 + wave * 64;
    float* base1 = ws + WS_CANDE + (c0 + 1) * 512 + wave * 64;
    compact64<PER>(k0, T0, base0, lane);
    compact64<PER>(k1, T1, base1, lane);
  }
}

// ------- kernel 3b: merge candidates/column -> exact top-64 sum -------
// One wave per column; 2048 waves = 256 blocks x 512 threads.
__global__ __launch_bounds__(512) void merge_kernel(
    const float* __restrict__ wsro, float* __restrict__ ws) {
  int gw = (blockIdx.x * 512 + threadIdx.x) >> 6;  // column id
  int lane = threadIdx.x & 63;
  if (gw < N_) {
    float s = final_sum<16>(wsro + WS_CANDI + gw * 1024, lane);
    if (lane == 0) ws[WS_CS_INTRA + gw] = s;
  } else {
    float s = final_sum<8>(wsro + WS_CANDE + (gw - N_) * 512, lane);
    if (lane == 0) ws[WS_CS_INTER + (gw - N_)] = s;
  }
}

// ---------------- kernel 4: final deterministic reduce ----------------
__global__ __launch_bounds__(256) void reduce_kernel(
    const float* __restrict__ ws, float* __restrict__ out) {
  __shared__ double sbuf[256];
  __shared__ double tA;
  int tid = threadIdx.x;
  double sa = 0.0, sb = 0.0;
  for (int i = tid; i < N_; i += 256) {
    sa += (double)ws[WS_CS_INTRA + i];
    sb += (double)ws[WS_CS_INTER + i];
  }
  sbuf[tid] = sa;
  __syncthreads();
  for (int off = 128; off > 0; off >>= 1) {
    if (tid < off) sbuf[tid] += sbuf[tid + off];
    __syncthreads();
  }
  if (tid == 0) tA = sbuf[0];
  __syncthreads();
  sbuf[tid] = sb;
  __syncthreads();
  for (int off = 128; off > 0; off >>= 1) {
    if (tid < off) sbuf[tid] += sbuf[tid + off];
    __syncthreads();
  }
  if (tid == 0) {
    double denom = (double)N_ * (double)K_;
    out[0] = (float)(tA / denom - 0.1 * (sbuf[0] / denom));
  }
}

extern "C" void kernel_launch(void* const* d_in, const int* in_sizes, int n_in,
                              void* d_out, int out_size, void* d_ws,
                              size_t ws_size, hipStream_t stream) {
  const float* outputs = (const float*)d_in[0];
  const float* targets = (const float*)d_in[1];
  const void* mask = d_in[2];
  float* ws = (float*)d_ws;

  hipLaunchKernelGGL(stats_part_kernel, dim3(NPART), dim3(256), 0, stream,
                     targets, mask, ws);
  hipLaunchKernelGGL(stats_fin_kernel, dim3(1), dim3(64), 0, stream, ws);
  hipLaunchKernelGGL(pre_kernel, dim3((BM_ + BN_ + 255) / 256), dim3(256), 0,
                     stream, outputs, targets, mask, ws);
  hipLaunchKernelGGL(select_kernel, dim3(N_ + N_ / 2), dim3(TSEL), 0, stream,
                     outputs, ws, ws);
  hipLaunchKernelGGL(merge_kernel, dim3(2 * N_ / 8), dim3(512), 0, stream,
                     ws, ws);
  hipLaunchKernelGGL(reduce_kernel, dim3(1), dim3(256), 0, stream, ws,
                     (float*)d_out);
}

// Round 9
// 70.792 us; speedup vs baseline: 2.0978x; 1.0714x over previous
//
#include <hip/hip_runtime.h>
#include <math.h>

#define B_ 4
#define N_ 1024
#define M_ 2048
#define D_ 9
#define K_ 64
#define BM_ (B_*M_)   // 8192 targets
#define BN_ (B_*N_)   // 4096 preds
#define TPRE_STRIDE 12
#define PPRE_STRIDE 12
#define NPART 32      // stats partial blocks
#define NSTAT 55      // 1 + 9 + 45 accumulators
#define TSEL 512      // select kernel block size (8 waves)
#define BUD 128       // per-wave candidate budget (>= K_, exactness-safe)

// workspace layout (in floats)
#define WS_A 0                                   // 81 (unused now, layout keep)
#define WS_MEAN 81                               // 9
#define WS_TPRE 96                               // 8192*12: [Au(9), uAu, pad, pad]
#define WS_PPRE (WS_TPRE + BM_*TPRE_STRIDE)      // 4096*12: [Aq(9), qAq, yAy, pad]
#define WS_CS_INTRA (WS_PPRE + BN_*PPRE_STRIDE)  // 1024 per-column sums
#define WS_CS_INTER (WS_CS_INTRA + N_)           // 1024
#define WS_PART (WS_CS_INTER + N_)               // 32*56 stats partials
#define WS_CANDI (WS_PART + NPART*(NSTAT+1))     // intra: 1024 cols * 2048
#define WS_CANDE (WS_CANDI + 1024*2048)          // inter: 1024 cols * 1024

__device__ __forceinline__ unsigned f2key(float f) {
  unsigned b = __float_as_uint(f);
  return (b & 0x80000000u) ? ~b : (b | 0x80000000u);
}
__device__ __forceinline__ float key2f(unsigned k) {
  unsigned b = (k & 0x80000000u) ? (k ^ 0x80000000u) : ~k;
  return __uint_as_float(b);
}

// mask dtype auto-detect from first 8192 bytes. 0=u8/bool, 1=int32, 2=int64.
__device__ int detect_mask_fmt(const void* mask, int* flags /*shared[2]*/) {
  int tid = threadIdx.x;
  if (tid < 2) flags[tid] = 0;
  __syncthreads();
  const unsigned char* mb = (const unsigned char*)mask;
  int la = 0, lb = 0;
  for (int i = tid; i < BM_; i += blockDim.x) {
    unsigned char c = mb[i];
    if (c) { if (i & 3) la = 1; else if ((i & 7) == 4) lb = 1; }
  }
  if (la) atomicOr(&flags[0], 1);
  if (lb) atomicOr(&flags[1], 1);
  __syncthreads();
  return flags[0] ? 0 : (flags[1] ? 1 : 2);
}
__device__ __forceinline__ int mask_at(const void* mask, int fmt, int t) {
  if (fmt == 0) return ((const unsigned char*)mask)[t] != 0;
  if (fmt == 1) return ((const int*)mask)[t] != 0;
  return ((const long long*)mask)[t] != 0LL;
}

// -------- kernel 1: per-block partial stats (S, Σt, Σ t tᵀ) in f32 --------
__global__ __launch_bounds__(256) void stats_part_kernel(
    const float* __restrict__ targets, const void* __restrict__ mask,
    float* __restrict__ ws) {
  __shared__ int flags[2];
  __shared__ float wpart[4][NSTAT];
  int tid = threadIdx.x;
  int fmt = detect_mask_fmt(mask, flags);
  int t = blockIdx.x * 256 + tid;  // one target per thread (BM_ = 32*256)

  float v[NSTAT];
  float tv[D_];
  int m = mask_at(mask, fmt, t);
  const float* tp = targets + t * D_;
#pragma unroll
  for (int d = 0; d < D_; ++d) tv[d] = m ? tp[d] : 0.f;
  v[0] = m ? 1.f : 0.f;
#pragma unroll
  for (int d = 0; d < D_; ++d) v[1 + d] = tv[d];
  {
    int p = 10;
#pragma unroll
    for (int i = 0; i < D_; ++i)
#pragma unroll
      for (int j = i; j < D_; ++j, ++p) v[p] = tv[i] * tv[j];
  }
#pragma unroll
  for (int off = 32; off > 0; off >>= 1)
#pragma unroll
    for (int p = 0; p < NSTAT; ++p) v[p] += __shfl_down(v[p], off);
  int wave = tid >> 6, lane = tid & 63;
  if (lane == 0)
#pragma unroll
    for (int p = 0; p < NSTAT; ++p) wpart[wave][p] = v[p];
  __syncthreads();
  if (tid < NSTAT) {
    float s = wpart[0][tid] + wpart[1][tid] + wpart[2][tid] + wpart[3][tid];
    ws[WS_PART + blockIdx.x * (NSTAT + 1) + tid] = s;
  }
}

// -------- kernel 2: combine stats (wave-0 replicated), invert, precompute --------
// Covariance is SPD (cond ~1) -> pivot-free lane-parallel Gauss-Jordan.
__global__ __launch_bounds__(256) void pre_kernel(
    const float* __restrict__ outputs, const float* __restrict__ targets,
    const void* __restrict__ mask, float* __restrict__ ws) {
  __shared__ int flags[2];
  __shared__ float tot[NSTAT];
  __shared__ float Atmp[9][9];
  __shared__ float Ash[81];
  __shared__ float msh[D_];
  int tid = threadIdx.x;
  int fmt = detect_mask_fmt(mask, flags);
  if (tid < NSTAT) {
    double s = 0.0;
    for (int b = 0; b < NPART; ++b)
      s += (double)ws[WS_PART + b * (NSTAT + 1) + tid];
    tot[tid] = (float)s;
  }
  __syncthreads();
  if (tid < 64) {
    int lane = tid;
    float S = tot[0];
    float col[9];
    int j = lane - 9;
    if (lane < 9) {
      float mj = tot[1 + lane] / S;
#pragma unroll
      for (int r = 0; r < 9; ++r) {
        float mr = tot[1 + r] / S;
        int i0 = r < lane ? r : lane;
        int j0 = r < lane ? lane : r;
        int p = i0 * 9 - (i0 * (i0 - 1)) / 2 + (j0 - i0);
        col[r] = (tot[10 + p] - S * mr * mj) / (S - 1.0f);
      }
    } else {
#pragma unroll
      for (int r = 0; r < 9; ++r) col[r] = (r == j) ? 1.f : 0.f;
    }
#pragma unroll
    for (int c = 0; c < 9; ++c) {
      float pv = __shfl(col[c], c);
      float inv = 1.f / pv;
      col[c] *= inv;
      float f[9];
#pragma unroll
      for (int r = 0; r < 9; ++r) f[r] = __shfl(col[r], c);
#pragma unroll
      for (int r = 0; r < 9; ++r)
        if (r != c) col[r] -= f[r] * col[c];
    }
    if (lane >= 9 && lane < 18) {
#pragma unroll
      for (int r = 0; r < 9; ++r) Atmp[r][j] = col[r];
    }
  }
  __syncthreads();
  if (tid < 9) msh[tid] = tot[1 + tid] / tot[0];
  for (int idx = tid; idx < 81; idx += 256) {
    int i0 = idx / 9, j0 = idx % 9;
    Ash[idx] = 0.5f * (Atmp[i0][j0] + Atmp[j0][i0]);
  }
  __syncthreads();

  int idx = blockIdx.x * 256 + tid;
  if (idx < BM_) {
    const float* tp = targets + idx * D_;
    float u[D_];
#pragma unroll
    for (int d = 0; d < D_; ++d) u[d] = tp[d] - msh[d];
    float cu = 0.f; float au[D_];
#pragma unroll
    for (int i = 0; i < D_; ++i) {
      float s = 0.f;
#pragma unroll
      for (int j = 0; j < D_; ++j) s += Ash[i * D_ + j] * u[j];
      au[i] = s; cu += u[i] * s;
    }
    if (!mask_at(mask, fmt, idx)) cu = INFINITY;
    float* o = ws + WS_TPRE + idx * TPRE_STRIDE;
#pragma unroll
    for (int d = 0; d < D_; ++d) o[d] = au[d];
    o[9] = cu; o[10] = 0.f; o[11] = 0.f;
  } else if (idx < BM_ + BN_) {
    int r = idx - BM_;
    const float* yp = outputs + r * D_;
    float y[D_], q[D_], aq[D_];
#pragma unroll
    for (int d = 0; d < D_; ++d) { y[d] = yp[d]; q[d] = y[d] + msh[d]; }
    float cp = 0.f, cq = 0.f;
#pragma unroll
    for (int i = 0; i < D_; ++i) {
      float sy = 0.f, sq = 0.f;
#pragma unroll
      for (int j = 0; j < D_; ++j) {
        sy += Ash[i * D_ + j] * y[j];
        sq += Ash[i * D_ + j] * q[j];
      }
      cp += y[i] * sy;
      aq[i] = sq; cq += q[i] * sq;
    }
    float* o = ws + WS_PPRE + r * PPRE_STRIDE;
#pragma unroll
    for (int d = 0; d < D_; ++d) o[d] = aq[d];
    o[9] = cq; o[10] = cp; o[11] = 0.f;
  }
}

// ---- exact single-chain bisect (merge only) ----
template <int PER>
__device__ __forceinline__ unsigned bisect64(const unsigned* key) {
  unsigned kmin = 0xFFFFFFFFu;
#pragma unroll
  for (int j = 0; j < PER; ++j) kmin = key[j] < kmin ? key[j] : kmin;
  unsigned gmin = kmin, mmax = kmin;
#pragma unroll
  for (int off = 32; off > 0; off >>= 1) {
    unsigned a = (unsigned)__shfl_xor((int)gmin, off);
    unsigned b = (unsigned)__shfl_xor((int)mmax, off);
    gmin = a < gmin ? a : gmin;
    mmax = b > mmax ? b : mmax;
  }
  unsigned lo = gmin, hi = mmax;
  while (lo < hi) {
    unsigned mid = lo + ((hi - lo) >> 1);
    int cnt = 0;
#pragma unroll
    for (int j = 0; j < PER; ++j) cnt += __popcll(__ballot(key[j] <= mid));
    if (cnt >= K_) hi = mid; else lo = mid + 1;
  }
  return lo;
}

// ---- dual early-exit threshold: bisect only until count(<=hi) <= BUD.
// Invariants per chain: count(<=hi) >= 64; count(<=lo-1) < 64.
// Exit: strict=0 -> compact <=hi (64..BUD values); strict=1 (lo==hi, ties)
// -> compact <hi (<64 values), pads represent genuine tied elements.
template <int PER>
__device__ __forceinline__ void sel_thresh2(const unsigned* k0,
                                            const unsigned* k1,
                                            unsigned& T0o, unsigned& T1o,
                                            int& st0, int& st1) {
  unsigned mn0 = 0xFFFFFFFFu, mn1 = 0xFFFFFFFFu;
#pragma unroll
  for (int j = 0; j < PER; ++j) {
    mn0 = k0[j] < mn0 ? k0[j] : mn0;
    mn1 = k1[j] < mn1 ? k1[j] : mn1;
  }
  unsigned g0 = mn0, x0 = mn0, g1 = mn1, x1 = mn1;
#pragma unroll
  for (int off = 32; off > 0; off >>= 1) {
    unsigned a0 = (unsigned)__shfl_xor((int)g0, off);
    unsigned b0 = (unsigned)__shfl_xor((int)x0, off);
    unsigned a1 = (unsigned)__shfl_xor((int)g1, off);
    unsigned b1 = (unsigned)__shfl_xor((int)x1, off);
    g0 = a0 < g0 ? a0 : g0;  x0 = b0 > x0 ? b0 : x0;
    g1 = a1 < g1 ? a1 : g1;  x1 = b1 > x1 ? b1 : x1;
  }
  unsigned lo0 = g0, hi0 = x0, lo1 = g1, hi1 = x1;
  int c0 = 0, c1 = 0;
#pragma unroll
  for (int j = 0; j < PER; ++j) {
    c0 += __popcll(__ballot(k0[j] <= hi0));
    c1 += __popcll(__ballot(k1[j] <= hi1));
  }
  while (((lo0 < hi0) && (c0 > BUD)) || ((lo1 < hi1) && (c1 > BUD))) {
    int a0 = (lo0 < hi0) && (c0 > BUD);
    int a1 = (lo1 < hi1) && (c1 > BUD);
    unsigned mid0 = lo0 + ((hi0 - lo0) >> 1);
    unsigned mid1 = lo1 + ((hi1 - lo1) >> 1);
    int n0 = 0, n1 = 0;
#pragma unroll
    for (int j = 0; j < PER; ++j) {
      n0 += __popcll(__ballot(k0[j] <= mid0));
      n1 += __popcll(__ballot(k1[j] <= mid1));
    }
    if (a0) { if (n0 >= K_) { hi0 = mid0; c0 = n0; } else lo0 = mid0 + 1; }
    if (a1) { if (n1 >= K_) { hi1 = mid1; c1 = n1; } else lo1 = mid1 + 1; }
  }
  T0o = hi0; st0 = (c0 > BUD);
  T1o = hi1; st1 = (c1 > BUD);
}

// ---- compact keys (<T if strict else <=T) into BUD slots, pad with T ----
template <int PER>
__device__ __forceinline__ void compactB(const unsigned* key, unsigned T,
                                         int strict, float* candw, int lane) {
  unsigned long long lmask = (1ull << lane) - 1ull;
  int n = 0;
#pragma unroll
  for (int j = 0; j < PER; ++j) {
    bool p = strict ? (key[j] < T) : (key[j] <= T);
    unsigned long long m = __ballot(p);
    if (p) candw[n + __popcll(m & lmask)] = key2f(key[j]);
    n += __popcll(m);
  }
  float tv = key2f(T);
  for (int i = n + lane; i < BUD; i += 64) candw[i] = tv;
}

// ---- exact sum of 64 smallest among NP*64 candidates (one wave) ----
template <int NP>
__device__ __forceinline__ float final_sum(const float* __restrict__ cand,
                                           int lane) {
  unsigned kk[NP];
#pragma unroll
  for (int j = 0; j < NP; ++j) kk[j] = f2key(cand[j * 64 + lane]);
  unsigned T = bisect64<NP>(kk);
  float s = 0.f; int c = 0;
#pragma unroll
  for (int j = 0; j < NP; ++j)
    if (kk[j] < T) { s += key2f(kk[j]); c++; }
#pragma unroll
  for (int off = 32; off > 0; off >>= 1) {
    s += __shfl_down(s, off);
    c += __shfl_down(c, off);
  }
  return s + (float)(K_ - c) * key2f(T);  // valid on lane 0
}

// ------- kernel 3: dual-column select, budgeted early-exit threshold -------
// bid<1024: intra pair p=bid>>1, half h=bid&1, cols {2p,2p+1}, rows [h*4096,+4096)
// bid>=1024: inter pair p=bid-1024, cols {2p,2p+1}, all 4096 rows.
__global__ __launch_bounds__(TSEL) void select_kernel(
    const float* __restrict__ outputs, const float* __restrict__ wsro,
    float* __restrict__ ws) {
  __shared__ float vsh[2][B_][D_];
  __shared__ float cvsh[2][B_];
  int tid = threadIdx.x, wave = tid >> 6, lane = tid & 63;
  int bid = blockIdx.x;
  int is_intra = bid < N_;
  int p = is_intra ? (bid >> 1) : (bid - N_);
  int h = is_intra ? (bid & 1) : 0;
  int c0 = 2 * p;
  if (tid < 2 * B_ * D_) {
    int c = tid / (B_ * D_), rem = tid % (B_ * D_), b = rem / D_, d = rem % D_;
    vsh[c][b][d] = outputs[(b * N_ + c0 + c) * D_ + d];
  }
  if (tid < 2 * B_) {
    int c = tid >> 2, b = tid & 3;
    cvsh[c][b] = wsro[WS_PPRE + (b * N_ + c0 + c) * PPRE_STRIDE + 10];
  }
  __syncthreads();
  constexpr int PER = 8;
  unsigned k0[PER], k1[PER];
  if (is_intra) {
    const float* pre = wsro + WS_TPRE;
    int rowbase = h * 4096;
#pragma unroll
    for (int bbb = 0; bbb < 2; ++bbb) {
      int b = 2 * h + bbb;  // wave-uniform
      float v0[D_], v1[D_];
#pragma unroll
      for (int d = 0; d < D_; ++d) { v0[d] = vsh[0][b][d]; v1[d] = vsh[1][b][d]; }
      float cv0 = cvsh[0][b], cv1 = cvsh[1][b];
#pragma unroll
      for (int jj = 0; jj < 4; ++jj) {
        int j = bbb * 4 + jj;  // (rowbase+tid+512j)>>11 == b
        const float* row = pre + (rowbase + tid + TSEL * j) * TPRE_STRIDE;
        float4 a0 = *(const float4*)row;
        float4 a1 = *(const float4*)(row + 4);
        float2 a2 = *(const float2*)(row + 8);
        float d0 = a0.x * v0[0] + a0.y * v0[1] + a0.z * v0[2] + a0.w * v0[3] +
                   a1.x * v0[4] + a1.y * v0[5] + a1.z * v0[6] + a1.w * v0[7] +
                   a2.x * v0[8];
        float d1 = a0.x * v1[0] + a0.y * v1[1] + a0.z * v1[2] + a0.w * v1[3] +
                   a1.x * v1[4] + a1.y * v1[5] + a1.z * v1[6] + a1.w * v1[7] +
                   a2.x * v1[8];
        k0[j] = f2key(a2.y + cv0 - 2.0f * d0);
        k1[j] = f2key(a2.y + cv1 - 2.0f * d1);
      }
      __builtin_amdgcn_sched_barrier(0);
    }
  } else {
    const float* pre = wsro + WS_PPRE;
#pragma unroll
    for (int bb = 0; bb < B_; ++bb) {
      float v0[D_], v1[D_];
#pragma unroll
      for (int d = 0; d < D_; ++d) { v0[d] = vsh[0][bb][d]; v1[d] = vsh[1][bb][d]; }
      float cv0 = cvsh[0][bb], cv1 = cvsh[1][bb];
#pragma unroll
      for (int jj = 0; jj < 2; ++jj) {
        int j = bb * 2 + jj;  // (tid+512j)>>10 == bb
        const float* row = pre + (tid + TSEL * j) * PPRE_STRIDE;
        float4 a0 = *(const float4*)row;
        float4 a1 = *(const float4*)(row + 4);
        float2 a2 = *(const float2*)(row + 8);
        float d0 = a0.x * v0[0] + a0.y * v0[1] + a0.z * v0[2] + a0.w * v0[3] +
                   a1.x * v0[4] + a1.y * v0[5] + a1.z * v0[6] + a1.w * v0[7] +
                   a2.x * v0[8];
        float d1 = a0.x * v1[0] + a0.y * v1[1] + a0.z * v1[2] + a0.w * v1[3] +
                   a1.x * v1[4] + a1.y * v1[5] + a1.z * v1[6] + a1.w * v1[7] +
                   a2.x * v1[8];
        k0[j] = f2key(a2.y + cv0 - 2.0f * d0);
        k1[j] = f2key(a2.y + cv1 - 2.0f * d1);
      }
      __builtin_amdgcn_sched_barrier(0);
    }
  }
  unsigned T0, T1; int st0, st1;
  sel_thresh2<PER>(k0, k1, T0, T1, st0, st1);
  if (is_intra) {
    compactB<PER>(k0, T0, st0,
                  ws + WS_CANDI + (c0) * 2048 + h * 1024 + wave * BUD, lane);
    compactB<PER>(k1, T1, st1,
                  ws + WS_CANDI + (c0 + 1) * 2048 + h * 1024 + wave * BUD, lane);
  } else {
    compactB<PER>(k0, T0, st0,
                  ws + WS_CANDE + (c0) * 1024 + wave * BUD, lane);
    compactB<PER>(k1, T1, st1,
                  ws + WS_CANDE + (c0 + 1) * 1024 + wave * BUD, lane);
  }
}

// ------- kernel 3b: merge candidates/column -> exact top-64 sum -------
__global__ __launch_bounds__(512) void merge_kernel(
    const float* __restrict__ wsro, float* __restrict__ ws) {
  int gw = (blockIdx.x * 512 + threadIdx.x) >> 6;  // column id
  int lane = threadIdx.x & 63;
  if (gw < N_) {
    float s = final_sum<32>(wsro + WS_CANDI + gw * 2048, lane);
    if (lane == 0) ws[WS_CS_INTRA + gw] = s;
  } else {
    float s = final_sum<16>(wsro + WS_CANDE + (gw - N_) * 1024, lane);
    if (lane == 0) ws[WS_CS_INTER + (gw - N_)] = s;
  }
}

// ---------------- kernel 4: final deterministic reduce ----------------
__global__ __launch_bounds__(256) void reduce_kernel(
    const float* __restrict__ ws, float* __restrict__ out) {
  __shared__ double sbuf[256];
  __shared__ double tA;
  int tid = threadIdx.x;
  double sa = 0.0, sb = 0.0;
  for (int i = tid; i < N_; i += 256) {
    sa += (double)ws[WS_CS_INTRA + i];
    sb += (double)ws[WS_CS_INTER + i];
  }
  sbuf[tid] = sa;
  __syncthreads();
  for (int off = 128; off > 0; off >>= 1) {
    if (tid < off) sbuf[tid] += sbuf[tid + off];
    __syncthreads();
  }
  if (tid == 0) tA = sbuf[0];
  __syncthreads();
  sbuf[tid] = sb;
  __syncthreads();
  for (int off = 128; off > 0; off >>= 1) {
    if (tid < off) sbuf[tid] += sbuf[tid + off];
    __syncthreads();
  }
  if (tid == 0) {
    double denom = (double)N_ * (double)K_;
    out[0] = (float)(tA / denom - 0.1 * (sbuf[0] / denom));
  }
}

extern "C" void kernel_launch(void* const* d_in, const int* in_sizes, int n_in,
                              void* d_out, int out_size, void* d_ws,
                              size_t ws_size, hipStream_t stream) {
  const float* outputs = (const float*)d_in[0];
  const float* targets = (const float*)d_in[1];
  const void* mask = d_in[2];
  float* ws = (float*)d_ws;

  hipLaunchKernelGGL(stats_part_kernel, dim3(NPART), dim3(256), 0, stream,
                     targets, mask, ws);
  hipLaunchKernelGGL(pre_kernel, dim3((BM_ + BN_ + 255) / 256), dim3(256), 0,
                     stream, outputs, targets, mask, ws);
  hipLaunchKernelGGL(select_kernel, dim3(N_ + N_ / 2), dim3(TSEL), 0, stream,
                     outputs, ws, ws);
  hipLaunchKernelGGL(merge_kernel, dim3(2 * N_ / 8), dim3(512), 0, stream,
                     ws, ws);
  hipLaunchKernelGGL(reduce_kernel, dim3(1), dim3(256), 0, stream, ws,
                     (float*)d_out);
}